// Round 4
// baseline (346.146 us; speedup 1.0000x reference)
//
#include <hip/hip_runtime.h>
#include <stdint.h>

// ---------------------------------------------------------------------------
// Fused attention, fp32 I/O, MI355X (gfx950).
// All GEMMs: C = A * B^T (NT), bf16 MFMA, fp32 accumulate.
// fp32 emulation (q/k/score chain): 3 K-segments  Ah*Bh + Al*Bh + Ah*Bl,
// expressed as virtual K=3072 with per-segment base pointers.
// Big GEMMs (qkproj, score): 256x256 8-phase schedule, counted vmcnt, setprio,
// and a 2-bit XOR LDS swizzle (row bits 2,3 -> column-chunk bits 1,2), applied
// as pre-swizzled global source + swizzled ds_read (LDS dest stays linear for
// global_load_lds). Small GEMMs: proven 128x128 kernel.
// ---------------------------------------------------------------------------

typedef __bf16 bf16_t;
typedef __bf16 bf16x8 __attribute__((ext_vector_type(8)));
typedef __bf16 bf16x4 __attribute__((ext_vector_type(4)));
typedef float  f32x4  __attribute__((ext_vector_type(4)));

__device__ __forceinline__ void gld_lds16(const void* g, void* l) {
    __builtin_amdgcn_global_load_lds(
        (const __attribute__((address_space(1))) void*)g,
        (__attribute__((address_space(3))) void*)l, 16, 0, 0);
}

// ======================= 256^2 8-phase GEMM (3 K-segments) ==================
// EPI 0: fp32 -> C0[bz*sC + row*ldc + col]
// EPI 2: split hi/lo bf16; col<1024 -> C0/C1 + row*1024+col, col>=1024 ->
//        same + 8388608 elems (the adjacent k-buffer).
template<int EPI>
__global__ __launch_bounds__(512, 2)
void gemm256(const bf16_t* __restrict__ A0, const bf16_t* __restrict__ A1,
             const bf16_t* __restrict__ A2,
             const bf16_t* __restrict__ B0, const bf16_t* __restrict__ B1,
             const bf16_t* __restrict__ B2,
             int NK, int lda, int ldb, long sA, long sB, long sC,
             void* __restrict__ C0v, void* __restrict__ C1v, int ldc,
             int nbx, int plane)
{
    // LDS: 2 buffers x [A0|A1|B0|B1] x 16KB = 128 KiB
    __shared__ __align__(1024) char smem[131072];

    const int nwg = (int)gridDim.x;
    int id = (int)blockIdx.x;
    id = (id & 7) * (nwg >> 3) + (id >> 3);      // XCD-contiguous, bijective
    const int bz  = id / plane;
    const int rem = id - bz * plane;
    const int by  = rem / nbx;
    const int bx  = rem - by * nbx;
    const long bm = (long)by * 256;
    const long bn = (long)bx * 256;
    const long zA = (long)bz * sA, zB = (long)bz * sB;

    const int tid  = threadIdx.x;
    const int lane = tid & 63;
    const int wid  = tid >> 6;        // 8 waves: 2(M) x 4(N)
    const int wr   = wid >> 2;
    const int wc   = wid & 3;
    const int fr   = lane & 15;
    const int kg   = lane >> 4;

    // staging: thread t covers chunk-row t>>3 (+64 via c), 16B chunk t&7, with
    // the 2-bit involution pre-applied to the GLOBAL source: chunk ^= row-bits
    // {2,3} -> chunk-bits {1,2}. (srow&4 = t&32, srow&8 = t&64.)
    const int srow = tid >> 3;
    const int scol = ((tid & 7) ^ ((tid >> 4) & 6)) << 3;   // elems
    const int ldsw = wid << 10;

    // read-side: same involution on the column byte (bits 5 and 6):
    // lds_byte(row, colb) = row*128 + (colb ^ ((row&12)<<3)); row bits 2,3 = fr&12
    const int swzb    = (fr & 12) << 3;                     // {0,32,64,96}
    const int koff[2] = { (kg * 16) ^ swzb, (64 + kg * 16) ^ swzb };
    const int aBase   = wr * 16384 + fr * 128;
    const int bBase   = 32768 + (wc >> 1) * 16384 + (wc & 1) * 8192 + fr * 128;

    f32x4  acc[8][4] = {};
    bf16x8 bfr[4][2];

    auto stage = [&](int kt, int part, int buf) {
        // part: 0=B-half0, 1=B-half1, 2=A-half0, 3=A-half1 (B-first order)
        const int seg    = kt >> 4;              // segLen = 1024 = 16 K-tiles
        const int klocal = (kt & 15) << 6;
        const bool isB = part < 2;
        const bf16_t* base;
        if (isB) base = (seg == 0) ? B0 : (seg == 1 ? B1 : B2);
        else     base = (seg == 0) ? A0 : (seg == 1 ? A1 : A2);
        const long rowb = (isB ? (bn + part * 128) : (bm + (part - 2) * 128)) + srow;
        const long zoff = isB ? zB : zA;
        const int  ld   = isB ? ldb : lda;
        const int  poff = isB ? (32768 + part * 16384) : ((part - 2) * 16384);
        #pragma unroll
        for (int c = 0; c < 2; ++c) {
            const bf16_t* g = base + zoff + (rowb + c * 64) * (long)ld + klocal + scol;
            gld_lds16(g, smem + buf * 65536 + poff + c * 8192 + ldsw);
        }
    };

    // prologue: tile0 {B0,B1,A0,A1} + tile1 {B0,B1,A0} = 7 half-tiles
    #pragma unroll
    for (int ht = 0; ht < 7; ++ht) stage(ht >> 2, ht & 3, (ht >> 2) & 1);
    asm volatile("s_waitcnt vmcnt(6)" ::: "memory");
    __builtin_amdgcn_s_barrier();

    const int NI = NK >> 1;
    #pragma unroll 1
    for (int i = 0; i < NI; ++i) {
        const bool last = (i == NI - 1);
        #pragma unroll
        for (int p = 0; p < 8; ++p) {
            const int q  = p & 3;
            const int lt = p >> 2;               // 0: tile 2i (buf0), 1: 2i+1
            const int cb = lt * 65536;
            if (q == 0) {                        // B-frags for this K-tile
                #pragma unroll
                for (int fn = 0; fn < 4; ++fn)
                    #pragma unroll
                    for (int kh = 0; kh < 2; ++kh)
                        bfr[fn][kh] = *(const bf16x8*)(smem + cb + bBase
                                                       + fn * 2048 + koff[kh]);
            }
            bf16x8 afr[2][2];                    // A-frags, quadrant q
            #pragma unroll
            for (int m2 = 0; m2 < 2; ++m2)
                #pragma unroll
                for (int kh = 0; kh < 2; ++kh)
                    afr[m2][kh] = *(const bf16x8*)(smem + cb + aBase
                                   + (q * 2 + m2) * 2048 + koff[kh]);
            // stage half-tile H_{8i+7+p}
            const int sc = (7 + p) >> 2;         // 1..3
            if (p == 0 || !last) stage(2 * i + sc, (7 + p) & 3, sc & 1);
            __builtin_amdgcn_s_barrier();
            asm volatile("s_waitcnt lgkmcnt(0)" ::: "memory");
            __builtin_amdgcn_s_setprio(1);
            #pragma unroll
            for (int m2 = 0; m2 < 2; ++m2)
                #pragma unroll
                for (int fn = 0; fn < 4; ++fn)
                    #pragma unroll
                    for (int kh = 0; kh < 2; ++kh)
                        acc[q * 2 + m2][fn] = __builtin_amdgcn_mfma_f32_16x16x32_bf16(
                            afr[m2][kh], bfr[fn][kh], acc[q * 2 + m2][fn], 0, 0, 0);
            __builtin_amdgcn_s_setprio(0);
            if (q == 3) {                        // counted vmcnt, never 0 mid-loop
                if (last) asm volatile("s_waitcnt vmcnt(0)" ::: "memory");
                else      asm volatile("s_waitcnt vmcnt(6)" ::: "memory");
            }
            __builtin_amdgcn_s_barrier();
        }
    }

    // C/D: col = lane&15, row = (lane>>4)*4 + reg
    const int rq = kg * 4;
    #pragma unroll
    for (int m = 0; m < 8; ++m) {
        #pragma unroll
        for (int fn = 0; fn < 4; ++fn) {
            const long col = bn + wc * 64 + fn * 16 + fr;
            #pragma unroll
            for (int r = 0; r < 4; ++r) {
                const long row = bm + wr * 128 + m * 16 + rq + r;
                const float v = acc[m][fn][r];
                if constexpr (EPI == 0) {
                    ((float*)C0v)[(long)bz * sC + row * ldc + col] = v;
                } else {
                    const bf16_t h  = (bf16_t)v;
                    const float  lo = v - (float)h;
                    const long off = (col >= 1024)
                        ? 8388608L + row * 1024 + (col - 1024)
                        : row * 1024 + col;
                    ((bf16_t*)C0v)[off] = h;
                    ((bf16_t*)C1v)[off] = (bf16_t)lo;
                }
            }
        }
    }
}

// ======================= 128^2 plain GEMM (proven, round 2) =================
#define BM 128
#define BN 128
#define BK 32

template<int EPI>   // 0 = fp32 C ; 1 = bf16 C
__global__ __launch_bounds__(256, 2)
void gemm_nt(const bf16_t* __restrict__ A, const bf16_t* __restrict__ B,
             int K, int lda, int ldb, long sA, long sB, long sC,
             void* __restrict__ C0v, int ldc, int nbx, int nby)
{
    __shared__ bf16_t As[BM * BK];
    __shared__ bf16_t Bs[BN * BK];

    const int nwg = (int)gridDim.x;
    int id = (int)blockIdx.x;
    id = (id & 7) * (nwg >> 3) + (id >> 3);
    const int plane = nbx * nby;
    const int bz  = id / plane;
    const int rem = id - bz * plane;
    const int by  = rem / nbx;
    const int bx  = rem - by * nbx;

    const long bm = (long)by * BM;
    const long bn = (long)bx * BN;

    const bf16_t* A0 = A + (long)bz * sA;
    const bf16_t* B0 = B + (long)bz * sB;

    const int tid  = threadIdx.x;
    const int lane = tid & 63;
    const int wid  = tid >> 6;
    const int wr   = wid >> 1;
    const int wc   = wid & 1;

    const int srow = tid >> 2;
    const int sgc  = (((tid & 3) ^ (srow & 3)) << 3);
    const int ldsb = wid * 512;

    const int fr  = lane & 15;
    const int kgs = (((lane >> 4) ^ (lane & 3)) << 3);

    f32x4 acc[4][4] = {};

    const long arow = (bm + srow) * (long)lda;
    const long brow = (bn + srow) * (long)ldb;

    for (int k0 = 0; k0 < K; k0 += BK) {
        const bf16_t* a = A0 + arow + k0 + sgc;
        const bf16_t* b = B0 + brow + k0 + sgc;
        gld_lds16(a,             &As[ldsb]);
        gld_lds16(a + 64L * lda, &As[2048 + ldsb]);
        gld_lds16(b,             &Bs[ldsb]);
        gld_lds16(b + 64L * ldb, &Bs[2048 + ldsb]);
        __syncthreads();

        bf16x8 af[4], bg[4];
        #pragma unroll
        for (int m = 0; m < 4; ++m)
            af[m] = *(const bf16x8*)&As[(wr * 64 + m * 16 + fr) * BK + kgs];
        #pragma unroll
        for (int n = 0; n < 4; ++n)
            bg[n] = *(const bf16x8*)&Bs[(wc * 64 + n * 16 + fr) * BK + kgs];
        #pragma unroll
        for (int m = 0; m < 4; ++m)
            #pragma unroll
            for (int n = 0; n < 4; ++n)
                acc[m][n] = __builtin_amdgcn_mfma_f32_16x16x32_bf16(
                    af[m], bg[n], acc[m][n], 0, 0, 0);
        __syncthreads();
    }

    const int rq = (lane >> 4) * 4;
    #pragma unroll
    for (int m = 0; m < 4; ++m) {
        #pragma unroll
        for (int n = 0; n < 4; ++n) {
            const long col = bn + wc * 64 + n * 16 + fr;
            #pragma unroll
            for (int r = 0; r < 4; ++r) {
                const long row = bm + wr * 64 + m * 16 + rq + r;
                const long idx = (long)bz * sC + row * ldc + col;
                const float v = acc[m][n][r];
                if constexpr (EPI == 0) ((float*)C0v)[idx]  = v;
                else                    ((bf16_t*)C0v)[idx] = (bf16_t)v;
            }
        }
    }
}

// =========================== helpers ========================================
template<bool SPLIT>
__global__ __launch_bounds__(256)
void cvt_f32_bf16(const float* __restrict__ X, bf16_t* __restrict__ Hh,
                  bf16_t* __restrict__ Ll, int n)
{
    const int i = (blockIdx.x * 256 + threadIdx.x) * 4;
    if (i >= n) return;
    const f32x4 v = *(const f32x4*)&X[i];
    bf16x4 h, l;
    #pragma unroll
    for (int j = 0; j < 4; ++j) {
        h[j] = (bf16_t)v[j];
        if constexpr (SPLIT) l[j] = (bf16_t)(v[j] - (float)h[j]);
    }
    *(bf16x4*)&Hh[i] = h;
    if constexpr (SPLIT) *(bf16x4*)&Ll[i] = l;
}

__global__ __launch_bounds__(256)
void softmax_rows(const float* __restrict__ Sc, bf16_t* __restrict__ P)
{
    constexpr int NC = 2048;
    const int row = blockIdx.x;
    const int tid = threadIdx.x;
    const float* s = Sc + (size_t)row * NC;

    float v[8];
    *(f32x4*)&v[0] = *(const f32x4*)&s[tid * 8];
    *(f32x4*)&v[4] = *(const f32x4*)&s[tid * 8 + 4];

    float m = v[0];
    #pragma unroll
    for (int j = 1; j < 8; ++j) m = fmaxf(m, v[j]);
    #pragma unroll
    for (int off = 1; off < 64; off <<= 1) m = fmaxf(m, __shfl_xor(m, off));

    __shared__ float redm[4], reds[4];
    if ((tid & 63) == 0) redm[tid >> 6] = m;
    __syncthreads();
    m = fmaxf(fmaxf(redm[0], redm[1]), fmaxf(redm[2], redm[3]));

    float sum = 0.f;
    #pragma unroll
    for (int j = 0; j < 8; ++j) { v[j] = __expf(v[j] - m); sum += v[j]; }
    #pragma unroll
    for (int off = 1; off < 64; off <<= 1) sum += __shfl_xor(sum, off);
    if ((tid & 63) == 0) reds[tid >> 6] = sum;
    __syncthreads();
    sum = reds[0] + reds[1] + reds[2] + reds[3];

    const float inv = 1.0f / sum;
    bf16x8 o;
    #pragma unroll
    for (int j = 0; j < 8; ++j) o[j] = (bf16_t)(v[j] * inv);
    *(bf16x8*)(P + (size_t)row * NC + tid * 8) = o;
}

// =========================== driver =========================================
extern "C" void kernel_launch(void* const* d_in, const int* in_sizes, int n_in,
                              void* d_out, int out_size, void* d_ws, size_t ws_size,
                              hipStream_t stream)
{
    const float* x  = (const float*)d_in[0];
    const float* Wq = (const float*)d_in[1];
    const float* Wk = (const float*)d_in[2];
    const float* Wv = (const float*)d_in[3];
    const float* Wo = (const float*)d_in[4];
    float* out = (float*)d_out;

    constexpr long H = 1024, S = 2048, B = 4, NT = B * S;   // 8192 tokens
    constexpr long HH = H * H;

    // Workspace (peak footprint 146 MB, stream-ordered aliasing):
    //  [0,16)   xh        -> later score [0,64) fp32
    //  [16,32)  xl
    //  [32,36)  whi [2048][1024] (Wq rows 0-1023, Wk rows 1024-2047)
    //  [36,40)  wlo
    //  [40,42)  wv
    //  [64,80)  qh   -> later P [64,96) bf16
    //  [80,96)  kh
    //  [96,112) ql   -> later attn [96,112)
    //  [112,128) kl
    //  [128,144) vT [1024][8192]
    //  [144,146) wo
    char* ws = (char*)d_ws;
    const size_t MB = 1u << 20;
    bf16_t* xh    = (bf16_t*)(ws + 0);
    bf16_t* xl    = (bf16_t*)(ws + 16 * MB);
    bf16_t* whi   = (bf16_t*)(ws + 32 * MB);
    bf16_t* wlo   = (bf16_t*)(ws + 36 * MB);
    bf16_t* wv    = (bf16_t*)(ws + 40 * MB);
    float*  score = (float*) (ws + 0);
    bf16_t* qh    = (bf16_t*)(ws + 64 * MB);
    bf16_t* kh    = (bf16_t*)(ws + 80 * MB);   // = qh + 8388608 elems
    bf16_t* ql    = (bf16_t*)(ws + 96 * MB);
    bf16_t* kl    = (bf16_t*)(ws + 112 * MB);  // = ql + 8388608 elems
    bf16_t* P     = (bf16_t*)(ws + 64 * MB);
    bf16_t* attn  = (bf16_t*)(ws + 96 * MB);
    bf16_t* vT    = (bf16_t*)(ws + 128 * MB);
    bf16_t* wo    = (bf16_t*)(ws + 144 * MB);

    const dim3 blk(256);

    // conversions / splits
    cvt_f32_bf16<true ><<<NT * H / 1024, blk, 0, stream>>>(x,  xh, xl, NT * H);
    cvt_f32_bf16<true ><<<HH / 1024, blk, 0, stream>>>(Wq, whi,      wlo,      HH);
    cvt_f32_bf16<true ><<<HH / 1024, blk, 0, stream>>>(Wk, whi + HH, wlo + HH, HH);
    cvt_f32_bf16<false><<<HH / 1024, blk, 0, stream>>>(Wv, wv, nullptr, HH);
    cvt_f32_bf16<false><<<HH / 1024, blk, 0, stream>>>(Wo, wo, nullptr, HH);

    // q,k projection: [8192][3072] x [2048][3072]^T, split epilogue
    gemm256<2><<<dim3(256), dim3(512), 0, stream>>>(
        xh, xl, xh, whi, whi, wlo, 48, (int)H, (int)H, 0L, 0L, 0L,
        qh, ql, (int)H, 8, 256);

    // vT[e,t] = sum_d Wv[e,d] x[t,d]
    gemm_nt<1><<<dim3(512), blk, 0, stream>>>(
        wv, xh, (int)H, (int)H, (int)H, 0L, 0L, 0L, vT, (int)NT, 64, 8);

    // score = q k^T (4 batches, virtual K=3072, fp32 out, unscaled)
    gemm256<0><<<dim3(256), dim3(512), 0, stream>>>(
        qh, ql, qh, kh, kh, kl, 48, (int)H, (int)H,
        S * H, S * H, S * S, score, nullptr, (int)S, 8, 64);

    // softmax rows (all batches)
    softmax_rows<<<dim3(B * S), blk, 0, stream>>>(score, P);

    // attn = P v  ==  P * (vT batch-slice)^T
    gemm_nt<1><<<dim3(512), blk, 0, stream>>>(
        P, vT, (int)S, (int)S, (int)NT, S * S, S, S * H, attn, (int)H, 8, 16);

    // out = attn Wo^T
    gemm_nt<0><<<dim3(512), blk, 0, stream>>>(
        attn, wo, (int)H, (int)H, (int)H, 0L, 0L, 0L, out, (int)H, 8, 64);
}

// Round 5
// 340.016 us; speedup vs baseline: 1.0180x; 1.0180x over previous
//
#include <hip/hip_runtime.h>
#include <stdint.h>

// ---------------------------------------------------------------------------
// Fused attention, fp32 I/O, MI355X (gfx950).
// All GEMMs: C = A * B^T (NT), bf16 MFMA, fp32 accumulate.
// fp32 emulation (q/k/score chain): 3 K-segments  Ah*Bh + Al*Bh + Ah*Bl,
// expressed as virtual K=3072 with per-segment base pointers.
// Big GEMMs (qkproj, score): 256x256 8-phase schedule, counted vmcnt, setprio.
// Fragment LDS reads are INLINE-ASM ds_read_b128 (invisible to the compiler's
// waitcnt insertion, so the counted-vmcnt pipeline isn't drained per phase);
// correctness owned by explicit lgkmcnt(0)+sched_barrier (rule #18) and the
// vmcnt(6) ladder. Small GEMMs: proven 128x128 kernel.
// ---------------------------------------------------------------------------

typedef __bf16 bf16_t;
typedef __bf16 bf16x8 __attribute__((ext_vector_type(8)));
typedef __bf16 bf16x4 __attribute__((ext_vector_type(4)));
typedef float  f32x4  __attribute__((ext_vector_type(4)));
typedef uint32_t u32;

__device__ __forceinline__ void gld_lds16(const void* g, void* l) {
    __builtin_amdgcn_global_load_lds(
        (const __attribute__((address_space(1))) void*)g,
        (__attribute__((address_space(3))) void*)l, 16, 0, 0);
}

// inline-asm LDS read: compiler cannot see this as an LDS op, so it neither
// reorders it past our counted waits nor inserts conservative vmcnt drains.
__device__ __forceinline__ bf16x8 ld128(const void* p) {
    bf16x8 r;
    const u32 a = (u32)(uintptr_t)(__attribute__((address_space(3))) const void*)p;
    asm volatile("ds_read_b128 %0, %1" : "=v"(r) : "v"(a));
    return r;
}

// ======================= 256^2 8-phase GEMM (3 K-segments) ==================
// EPI 0: fp32 -> C0[bz*sC + row*ldc + col]
// EPI 2: split hi/lo bf16; col<1024 -> C0/C1 + row*1024+col, col>=1024 ->
//        same + 8388608 elems (the adjacent k-buffer).
template<int EPI>
__global__ __launch_bounds__(512, 2)
void gemm256(const bf16_t* __restrict__ A0, const bf16_t* __restrict__ A1,
             const bf16_t* __restrict__ A2,
             const bf16_t* __restrict__ B0, const bf16_t* __restrict__ B1,
             const bf16_t* __restrict__ B2,
             int NK, int lda, int ldb, long sA, long sB, long sC,
             void* __restrict__ C0v, void* __restrict__ C1v, int ldc,
             int nbx, int plane)
{
    // LDS: 2 buffers x [A0|A1|B0|B1] x 16KB = 128 KiB
    __shared__ __align__(1024) char smem[131072];

    const int nwg = (int)gridDim.x;
    int id = (int)blockIdx.x;
    id = (id & 7) * (nwg >> 3) + (id >> 3);      // XCD-contiguous, bijective
    const int bz  = id / plane;
    const int rem = id - bz * plane;
    const int by  = rem / nbx;
    const int bx  = rem - by * nbx;
    const long bm = (long)by * 256;
    const long bn = (long)bx * 256;
    const long zA = (long)bz * sA, zB = (long)bz * sB;

    const int tid  = threadIdx.x;
    const int lane = tid & 63;
    const int wid  = tid >> 6;        // 8 waves: 2(M) x 4(N)
    const int wr   = wid >> 2;
    const int wc   = wid & 3;
    const int fr   = lane & 15;
    const int kg   = lane >> 4;

    // staging: thread t covers chunk-row t>>3 (+64 via c), 16B chunk t&7, with
    // the 2-bit involution pre-applied to the GLOBAL source: chunk ^= row-bits
    // {2,3} -> chunk-bits {1,2}. (srow&4 = t&32, srow&8 = t&64.)
    const int srow = tid >> 3;
    const int scol = ((tid & 7) ^ ((tid >> 4) & 6)) << 3;   // elems
    const int ldsw = wid << 10;

    // read-side: same involution on the column byte (bits 5 and 6):
    // lds_byte(row, colb) = row*128 + (colb ^ ((row&12)<<3)); row bits 2,3 = fr&12
    const int swzb    = (fr & 12) << 3;                     // {0,32,64,96}
    const int koff[2] = { (kg * 16) ^ swzb, (64 + kg * 16) ^ swzb };
    const int aBase   = wr * 16384 + fr * 128;
    const int bBase   = 32768 + (wc >> 1) * 16384 + (wc & 1) * 8192 + fr * 128;

    f32x4  acc[8][4] = {};
    bf16x8 bfr[4][2];

    auto stage = [&](int kt, int part, int buf) {
        // part: 0=B-half0, 1=B-half1, 2=A-half0, 3=A-half1 (B-first order)
        const int seg    = kt >> 4;              // segLen = 1024 = 16 K-tiles
        const int klocal = (kt & 15) << 6;
        const bool isB = part < 2;
        const bf16_t* base;
        if (isB) base = (seg == 0) ? B0 : (seg == 1 ? B1 : B2);
        else     base = (seg == 0) ? A0 : (seg == 1 ? A1 : A2);
        const long rowb = (isB ? (bn + part * 128) : (bm + (part - 2) * 128)) + srow;
        const long zoff = isB ? zB : zA;
        const int  ld   = isB ? ldb : lda;
        const int  poff = isB ? (32768 + part * 16384) : ((part - 2) * 16384);
        #pragma unroll
        for (int c = 0; c < 2; ++c) {
            const bf16_t* g = base + zoff + (rowb + c * 64) * (long)ld + klocal + scol;
            gld_lds16(g, smem + buf * 65536 + poff + c * 8192 + ldsw);
        }
    };

    // prologue: tile0 {B0,B1,A0,A1} + tile1 {B0,B1,A0} = 7 half-tiles
    #pragma unroll
    for (int ht = 0; ht < 7; ++ht) stage(ht >> 2, ht & 3, (ht >> 2) & 1);
    asm volatile("s_waitcnt vmcnt(6)" ::: "memory");
    __builtin_amdgcn_s_barrier();

    const int NI = NK >> 1;
    #pragma unroll 1
    for (int i = 0; i < NI; ++i) {
        const bool last = (i == NI - 1);
        #pragma unroll
        for (int p = 0; p < 8; ++p) {
            const int q  = p & 3;
            const int cb = (p >> 2) * 65536;     // 0: tile 2i (buf0), 1: 2i+1
            if (q == 0) {                        // B-frags for this K-tile
                #pragma unroll
                for (int fn = 0; fn < 4; ++fn)
                    #pragma unroll
                    for (int kh = 0; kh < 2; ++kh)
                        bfr[fn][kh] = ld128(smem + cb + bBase
                                            + fn * 2048 + koff[kh]);
            }
            bf16x8 afr[2][2];                    // A-frags, quadrant q
            #pragma unroll
            for (int m2 = 0; m2 < 2; ++m2)
                #pragma unroll
                for (int kh = 0; kh < 2; ++kh)
                    afr[m2][kh] = ld128(smem + cb + aBase
                                        + (q * 2 + m2) * 2048 + koff[kh]);
            // stage half-tile H_{8i+7+p}
            const int sc = (7 + p) >> 2;         // 1..3
            if (p == 0 || !last) stage(2 * i + sc, (7 + p) & 3, sc & 1);
            __builtin_amdgcn_sched_barrier(0);
            __builtin_amdgcn_s_barrier();
            asm volatile("s_waitcnt lgkmcnt(0)" ::: "memory");
            __builtin_amdgcn_sched_barrier(0);   // rule #18: pin MFMA below wait
            __builtin_amdgcn_s_setprio(1);
            #pragma unroll
            for (int m2 = 0; m2 < 2; ++m2)
                #pragma unroll
                for (int fn = 0; fn < 4; ++fn)
                    #pragma unroll
                    for (int kh = 0; kh < 2; ++kh)
                        acc[q * 2 + m2][fn] = __builtin_amdgcn_mfma_f32_16x16x32_bf16(
                            afr[m2][kh], bfr[fn][kh], acc[q * 2 + m2][fn], 0, 0, 0);
            __builtin_amdgcn_s_setprio(0);
            __builtin_amdgcn_sched_barrier(0);   // keep MFMA inside the phase
            if (q == 3) {                        // counted vmcnt, never 0 mid-loop
                if (last) asm volatile("s_waitcnt vmcnt(0)" ::: "memory");
                else      asm volatile("s_waitcnt vmcnt(6)" ::: "memory");
            }
            __builtin_amdgcn_s_barrier();
        }
    }

    // C/D: col = lane&15, row = (lane>>4)*4 + reg
    const int rq = kg * 4;
    #pragma unroll
    for (int m = 0; m < 8; ++m) {
        #pragma unroll
        for (int fn = 0; fn < 4; ++fn) {
            const long col = bn + wc * 64 + fn * 16 + fr;
            #pragma unroll
            for (int r = 0; r < 4; ++r) {
                const long row = bm + wr * 128 + m * 16 + rq + r;
                const float v = acc[m][fn][r];
                if constexpr (EPI == 0) {
                    ((float*)C0v)[(long)bz * sC + row * ldc + col] = v;
                } else {
                    const bf16_t h  = (bf16_t)v;
                    const float  lo = v - (float)h;
                    const long off = (col >= 1024)
                        ? 8388608L + row * 1024 + (col - 1024)
                        : row * 1024 + col;
                    ((bf16_t*)C0v)[off] = h;
                    ((bf16_t*)C1v)[off] = (bf16_t)lo;
                }
            }
        }
    }
}

// ======================= 128^2 plain GEMM (proven, round 2) =================
#define BM 128
#define BN 128
#define BK 32

template<int EPI>   // 0 = fp32 C ; 1 = bf16 C
__global__ __launch_bounds__(256, 2)
void gemm_nt(const bf16_t* __restrict__ A, const bf16_t* __restrict__ B,
             int K, int lda, int ldb, long sA, long sB, long sC,
             void* __restrict__ C0v, int ldc, int nbx, int nby)
{
    __shared__ bf16_t As[BM * BK];
    __shared__ bf16_t Bs[BN * BK];

    const int nwg = (int)gridDim.x;
    int id = (int)blockIdx.x;
    id = (id & 7) * (nwg >> 3) + (id >> 3);
    const int plane = nbx * nby;
    const int bz  = id / plane;
    const int rem = id - bz * plane;
    const int by  = rem / nbx;
    const int bx  = rem - by * nbx;

    const long bm = (long)by * BM;
    const long bn = (long)bx * BN;

    const bf16_t* A0 = A + (long)bz * sA;
    const bf16_t* B0 = B + (long)bz * sB;

    const int tid  = threadIdx.x;
    const int lane = tid & 63;
    const int wid  = tid >> 6;
    const int wr   = wid >> 1;
    const int wc   = wid & 1;

    const int srow = tid >> 2;
    const int sgc  = (((tid & 3) ^ (srow & 3)) << 3);
    const int ldsb = wid * 512;

    const int fr  = lane & 15;
    const int kgs = (((lane >> 4) ^ (lane & 3)) << 3);

    f32x4 acc[4][4] = {};

    const long arow = (bm + srow) * (long)lda;
    const long brow = (bn + srow) * (long)ldb;

    for (int k0 = 0; k0 < K; k0 += BK) {
        const bf16_t* a = A0 + arow + k0 + sgc;
        const bf16_t* b = B0 + brow + k0 + sgc;
        gld_lds16(a,             &As[ldsb]);
        gld_lds16(a + 64L * lda, &As[2048 + ldsb]);
        gld_lds16(b,             &Bs[ldsb]);
        gld_lds16(b + 64L * ldb, &Bs[2048 + ldsb]);
        __syncthreads();

        bf16x8 af[4], bg[4];
        #pragma unroll
        for (int m = 0; m < 4; ++m)
            af[m] = *(const bf16x8*)&As[(wr * 64 + m * 16 + fr) * BK + kgs];
        #pragma unroll
        for (int n = 0; n < 4; ++n)
            bg[n] = *(const bf16x8*)&Bs[(wc * 64 + n * 16 + fr) * BK + kgs];
        #pragma unroll
        for (int m = 0; m < 4; ++m)
            #pragma unroll
            for (int n = 0; n < 4; ++n)
                acc[m][n] = __builtin_amdgcn_mfma_f32_16x16x32_bf16(
                    af[m], bg[n], acc[m][n], 0, 0, 0);
        __syncthreads();
    }

    const int rq = (lane >> 4) * 4;
    #pragma unroll
    for (int m = 0; m < 4; ++m) {
        #pragma unroll
        for (int n = 0; n < 4; ++n) {
            const long col = bn + wc * 64 + n * 16 + fr;
            #pragma unroll
            for (int r = 0; r < 4; ++r) {
                const long row = bm + wr * 64 + m * 16 + rq + r;
                const long idx = (long)bz * sC + row * ldc + col;
                const float v = acc[m][n][r];
                if constexpr (EPI == 0) ((float*)C0v)[idx]  = v;
                else                    ((bf16_t*)C0v)[idx] = (bf16_t)v;
            }
        }
    }
}

// =========================== helpers ========================================
template<bool SPLIT>
__global__ __launch_bounds__(256)
void cvt_f32_bf16(const float* __restrict__ X, bf16_t* __restrict__ Hh,
                  bf16_t* __restrict__ Ll, int n)
{
    const int i = (blockIdx.x * 256 + threadIdx.x) * 4;
    if (i >= n) return;
    const f32x4 v = *(const f32x4*)&X[i];
    bf16x4 h, l;
    #pragma unroll
    for (int j = 0; j < 4; ++j) {
        h[j] = (bf16_t)v[j];
        if constexpr (SPLIT) l[j] = (bf16_t)(v[j] - (float)h[j]);
    }
    *(bf16x4*)&Hh[i] = h;
    if constexpr (SPLIT) *(bf16x4*)&Ll[i] = l;
}

__global__ __launch_bounds__(256)
void softmax_rows(const float* __restrict__ Sc, bf16_t* __restrict__ P)
{
    constexpr int NC = 2048;
    const int row = blockIdx.x;
    const int tid = threadIdx.x;
    const float* s = Sc + (size_t)row * NC;

    float v[8];
    *(f32x4*)&v[0] = *(const f32x4*)&s[tid * 8];
    *(f32x4*)&v[4] = *(const f32x4*)&s[tid * 8 + 4];

    float m = v[0];
    #pragma unroll
    for (int j = 1; j < 8; ++j) m = fmaxf(m, v[j]);
    #pragma unroll
    for (int off = 1; off < 64; off <<= 1) m = fmaxf(m, __shfl_xor(m, off));

    __shared__ float redm[4], reds[4];
    if ((tid & 63) == 0) redm[tid >> 6] = m;
    __syncthreads();
    m = fmaxf(fmaxf(redm[0], redm[1]), fmaxf(redm[2], redm[3]));

    float sum = 0.f;
    #pragma unroll
    for (int j = 0; j < 8; ++j) { v[j] = __expf(v[j] - m); sum += v[j]; }
    #pragma unroll
    for (int off = 1; off < 64; off <<= 1) sum += __shfl_xor(sum, off);
    if ((tid & 63) == 0) reds[tid >> 6] = sum;
    __syncthreads();
    sum = reds[0] + reds[1] + reds[2] + reds[3];

    const float inv = 1.0f / sum;
    bf16x8 o;
    #pragma unroll
    for (int j = 0; j < 8; ++j) o[j] = (bf16_t)(v[j] * inv);
    *(bf16x8*)(P + (size_t)row * NC + tid * 8) = o;
}

// =========================== driver =========================================
extern "C" void kernel_launch(void* const* d_in, const int* in_sizes, int n_in,
                              void* d_out, int out_size, void* d_ws, size_t ws_size,
                              hipStream_t stream)
{
    const float* x  = (const float*)d_in[0];
    const float* Wq = (const float*)d_in[1];
    const float* Wk = (const float*)d_in[2];
    const float* Wv = (const float*)d_in[3];
    const float* Wo = (const float*)d_in[4];
    float* out = (float*)d_out;

    constexpr long H = 1024, S = 2048, B = 4, NT = B * S;   // 8192 tokens
    constexpr long HH = H * H;

    // Workspace (peak footprint 146 MB, stream-ordered aliasing):
    //  [0,16)   xh        -> later score [0,64) fp32
    //  [16,32)  xl
    //  [32,36)  whi [2048][1024] (Wq rows 0-1023, Wk rows 1024-2047)
    //  [36,40)  wlo
    //  [40,42)  wv
    //  [64,80)  qh   -> later P [64,96) bf16
    //  [80,96)  kh
    //  [96,112) ql   -> later attn [96,112)
    //  [112,128) kl
    //  [128,144) vT [1024][8192]
    //  [144,146) wo
    char* ws = (char*)d_ws;
    const size_t MB = 1u << 20;
    bf16_t* xh    = (bf16_t*)(ws + 0);
    bf16_t* xl    = (bf16_t*)(ws + 16 * MB);
    bf16_t* whi   = (bf16_t*)(ws + 32 * MB);
    bf16_t* wlo   = (bf16_t*)(ws + 36 * MB);
    bf16_t* wv    = (bf16_t*)(ws + 40 * MB);
    float*  score = (float*) (ws + 0);
    bf16_t* qh    = (bf16_t*)(ws + 64 * MB);
    bf16_t* kh    = (bf16_t*)(ws + 80 * MB);   // = qh + 8388608 elems
    bf16_t* ql    = (bf16_t*)(ws + 96 * MB);
    bf16_t* kl    = (bf16_t*)(ws + 112 * MB);  // = ql + 8388608 elems
    bf16_t* P     = (bf16_t*)(ws + 64 * MB);
    bf16_t* attn  = (bf16_t*)(ws + 96 * MB);
    bf16_t* vT    = (bf16_t*)(ws + 128 * MB);
    bf16_t* wo    = (bf16_t*)(ws + 144 * MB);

    const dim3 blk(256);

    // conversions / splits
    cvt_f32_bf16<true ><<<NT * H / 1024, blk, 0, stream>>>(x,  xh, xl, NT * H);
    cvt_f32_bf16<true ><<<HH / 1024, blk, 0, stream>>>(Wq, whi,      wlo,      HH);
    cvt_f32_bf16<true ><<<HH / 1024, blk, 0, stream>>>(Wk, whi + HH, wlo + HH, HH);
    cvt_f32_bf16<false><<<HH / 1024, blk, 0, stream>>>(Wv, wv, nullptr, HH);
    cvt_f32_bf16<false><<<HH / 1024, blk, 0, stream>>>(Wo, wo, nullptr, HH);

    // q,k projection: [8192][3072] x [2048][3072]^T, split epilogue
    gemm256<2><<<dim3(256), dim3(512), 0, stream>>>(
        xh, xl, xh, whi, whi, wlo, 48, (int)H, (int)H, 0L, 0L, 0L,
        qh, ql, (int)H, 8, 256);

    // vT[e,t] = sum_d Wv[e,d] x[t,d]
    gemm_nt<1><<<dim3(512), blk, 0, stream>>>(
        wv, xh, (int)H, (int)H, (int)H, 0L, 0L, 0L, vT, (int)NT, 64, 8);

    // score = q k^T (4 batches, virtual K=3072, fp32 out, unscaled)
    gemm256<0><<<dim3(256), dim3(512), 0, stream>>>(
        qh, ql, qh, kh, kh, kl, 48, (int)H, (int)H,
        S * H, S * H, S * S, score, nullptr, (int)S, 8, 64);

    // softmax rows (all batches)
    softmax_rows<<<dim3(B * S), blk, 0, stream>>>(score, P);

    // attn = P v  ==  P * (vT batch-slice)^T
    gemm_nt<1><<<dim3(512), blk, 0, stream>>>(
        P, vT, (int)S, (int)S, (int)NT, S * S, S, S * H, attn, (int)H, 8, 16);

    // out = attn Wo^T
    gemm_nt<0><<<dim3(512), blk, 0, stream>>>(
        attn, wo, (int)H, (int)H, (int)H, 0L, 0L, 0L, out, (int)H, 8, 64);
}